// Round 18
// baseline (253.704 us; speedup 1.0000x reference)
//
#include <hip/hip_runtime.h>
#include <hip/hip_bf16.h>
#include <stdint.h>

#define QLEN 1024
#define MLEN 1024
#define KLEN 2048
#define BSZ 4
#define NH 16
#define DH 64
#define DM 1024

typedef __attribute__((ext_vector_type(8))) short bf16x8;
typedef __attribute__((ext_vector_type(4))) float f32x4;
typedef __attribute__((ext_vector_type(4))) unsigned int u32x4;
typedef __attribute__((ext_vector_type(2))) unsigned int u32x2;
typedef unsigned short u16;
typedef unsigned int u32;

typedef unsigned int __attribute__((address_space(1))) gu32;
typedef unsigned int __attribute__((address_space(3))) lu32;

__device__ __forceinline__ void stage16(const void* g, void* l){
  __builtin_amdgcn_global_load_lds((const gu32*)g, (lu32*)l, 16, 0, 0);
}

__device__ __forceinline__ u16 f2b(float f){
  u32 u = __builtin_bit_cast(u32, f);
  u32 r = (u + 0x7FFFu + ((u >> 16) & 1u)) >> 16;
  return (u16)r;
}
__device__ __forceinline__ float b2f(u16 v){
  u32 u = ((u32)v) << 16;
  return __builtin_bit_cast(float, u);
}
__device__ __forceinline__ u16 f2bn(float f){
  __hip_bfloat16 h = __float2bfloat16(f);
  u16 r; __builtin_memcpy(&r, &h, 2); return r;
}
__device__ __forceinline__ u32 pk2(float a, float b){
  float2 t; t.x = a; t.y = b;
  __hip_bfloat162 h = __float22bfloat162_rn(t);
  u32 r; __builtin_memcpy(&r, &h, 4); return r;
}

// XOR swizzle for [rows][64]bf16 tiles (128B rows)
__device__ __forceinline__ int swz(int row, int byteoff){
  return (row << 7) + (byteoff ^ (((row ^ (row >> 3)) & 7) << 4));
}

// 2x2 block-transpose swaps between two registers.
__device__ __forceinline__ u32x2 pl32sw(u32 a, u32 b){
#if __has_builtin(__builtin_amdgcn_permlane32_swap)
  auto t = __builtin_amdgcn_permlane32_swap(a, b, false, false);
  u32x2 o; __builtin_memcpy(&o, &t, 8); return o;
#else
  int sa = __shfl_xor((int)a, 32), sb = __shfl_xor((int)b, 32);
  int l = threadIdx.x & 63;
  u32x2 o;
  o.x = (l & 32) ? (u32)sb : a;
  o.y = (l & 32) ? b : (u32)sa;
  return o;
#endif
}
__device__ __forceinline__ u32x2 pl16sw(u32 a, u32 b){
#if __has_builtin(__builtin_amdgcn_permlane16_swap)
  auto t = __builtin_amdgcn_permlane16_swap(a, b, false, false);
  u32x2 o; __builtin_memcpy(&o, &t, 8); return o;
#else
  u32 sb = (u32)__builtin_amdgcn_ds_swizzle((int)b, 0x401F);
  u32 sa = (u32)__builtin_amdgcn_ds_swizzle((int)a, 0x401F);
  int l = threadIdx.x & 63;
  u32x2 o;
  o.x = (l & 16) ? sb : a;
  o.y = (l & 16) ? b : sa;
  return o;
#endif
}

#define MFMA16(a, b, c) __builtin_amdgcn_mfma_f32_16x16x32_bf16(a, b, c, 0, 0, 0)

// ---------------- prep: conversions + weight transposes, one launch ----------

__global__ __launch_bounds__(256) void prep_k(
    const float* __restrict__ mems, const float* __restrict__ w,
    const float* __restrict__ r,
    const float* __restrict__ s0, u16* __restrict__ d0,
    const float* __restrict__ s1, u16* __restrict__ d1,
    const float* __restrict__ s2, u16* __restrict__ d2,
    u16* __restrict__ catB, u16* __restrict__ rB)
{
  __shared__ float tile[32][33];
  int bx = blockIdx.x;
  if (bx < 8192){
    int idx = bx * 256 + threadIdx.x;
    const int memf4 = MLEN * BSZ * DM / 4;
    float4 v = (idx < memf4) ? ((const float4*)mems)[idx]
                             : ((const float4*)w)[idx - memf4];
    ushort4 o;
    o.x = f2b(v.x); o.y = f2b(v.y); o.z = f2b(v.z); o.w = f2b(v.w);
    ((ushort4*)catB)[idx] = o;
    return;
  }
  if (bx < 10240){
    int idx = (bx - 8192) * 256 + threadIdx.x;
    float4 v = ((const float4*)r)[idx];
    ushort4 o;
    o.x = f2b(v.x); o.y = f2b(v.y); o.z = f2b(v.z); o.w = f2b(v.w);
    ((ushort4*)rB)[idx] = o;
    return;
  }
  int t = bx - 10240;              // 0..5119
  int sub = t % 160, r0 = (t / 160) * 32;
  const float* src; u16* dst; int C, c0;
  if (sub < 96){ src = s0; dst = d0; C = 3 * DM; c0 = sub * 32; }
  else if (sub < 128){ src = s1; dst = d1; C = DM; c0 = (sub - 96) * 32; }
  else { src = s2; dst = d2; C = DM; c0 = (sub - 128) * 32; }
  int tx = threadIdx.x & 31, ty = threadIdx.x >> 5;
  #pragma unroll
  for (int rr = ty; rr < 32; rr += 8)
    tile[rr][tx] = src[(size_t)(r0 + rr) * C + c0 + tx];
  __syncthreads();
  #pragma unroll
  for (int rr = ty; rr < 32; rr += 8)
    dst[(size_t)(c0 + rr) * DM + r0 + tx] = f2b(tile[tx][rr]);
}

// ---------------- merged QKV + R projection GEMM (128x128, BK=32, 2-phase) ----
// XCD-swizzled (1664 % 8 == 0, cpx = 208): A-panels L2-local per XCD.

__global__ __launch_bounds__(256, 4) void gemm01(
    const u16* __restrict__ catB, const u16* __restrict__ WqkvT,
    const u16* __restrict__ rB,   const u16* __restrict__ WrT,
    u16* __restrict__ qo, u16* __restrict__ ko, u16* __restrict__ vo,
    u16* __restrict__ rh)
{
  __shared__ u16 As[2][128 * 32];
  __shared__ u16 Bs[2][128 * 32];
  const int tid = threadIdx.x;
  const int lane = tid & 63, w = tid >> 6;
  const int wr = w >> 1, wc = w & 1;
  const int lr = lane >> 4, lc = lane & 15;
  const int bx = blockIdx.x;
  const int bs = (bx & 7) * 208 + (bx >> 3);   // bijective XCD swizzle
  const bool isR = bs >= 1536;
  const u16* A  = isR ? rB : catB;
  const u16* Bt = isR ? WrT : WqkvT;
  const int bb  = isR ? bs - 1536 : bs;
  const int nbx = isR ? 8 : 24;
  const int m0 = (bb / nbx) * 128, n0 = (bb % nbx) * 128;
  const int K = DM;

  f32x4 acc[4][4];
  #pragma unroll
  for (int i = 0; i < 4; i++)
    #pragma unroll
    for (int j = 0; j < 4; j++)
      acc[i][j] = (f32x4){0.f, 0.f, 0.f, 0.f};

  #pragma unroll
  for (int rnd = 0; rnd < 2; rnd++){
    int c = rnd * 256 + tid;
    int row = c >> 2, kc = c & 3;
    stage16((const char*)A + ((size_t)(m0 + row) * K + kc * 8) * 2,
            (char*)As + c * 16);
    stage16((const char*)Bt + ((size_t)(n0 + row) * K + kc * 8) * 2,
            (char*)Bs + c * 16);
  }

  const int NK = K >> 5;
  for (int it = 0; it < NK; ++it){
    const int cur = it & 1, nxt = cur ^ 1;
    if (it + 1 < NK){
      const int k0 = (it + 1) << 5;
      #pragma unroll
      for (int rnd = 0; rnd < 2; rnd++){
        int c = rnd * 256 + tid;
        int row = c >> 2, kc = c & 3;
        stage16((const char*)A + ((size_t)(m0 + row) * K + k0 + kc * 8) * 2,
                (char*)As + nxt * 8192 + c * 16);
        stage16((const char*)Bt + ((size_t)(n0 + row) * K + k0 + kc * 8) * 2,
                (char*)Bs + nxt * 8192 + c * 16);
      }
      asm volatile("s_waitcnt vmcnt(4)" ::: "memory");
    } else {
      asm volatile("s_waitcnt vmcnt(0)" ::: "memory");
    }
    __builtin_amdgcn_s_barrier();

    bf16x8 af[4], bfr[4];
    #pragma unroll
    for (int mf = 0; mf < 4; mf++)
      af[mf] = *(const bf16x8*)((const char*)As + cur * 8192 +
                                (wr * 64 + mf * 16 + lc) * 64 + lr * 16);
    #pragma unroll
    for (int nf = 0; nf < 4; nf++)
      bfr[nf] = *(const bf16x8*)((const char*)Bs + cur * 8192 +
                                 (wc * 64 + nf * 16 + lc) * 64 + lr * 16);
    #pragma unroll
    for (int mf = 0; mf < 4; mf++)
      #pragma unroll
      for (int nf = 0; nf < 4; nf++)
        acc[mf][nf] = MFMA16(af[mf], bfr[nf], acc[mf][nf]);
    __builtin_amdgcn_s_barrier();
  }

  #pragma unroll
  for (int mf = 0; mf < 4; mf++){
    #pragma unroll
    for (int nf = 0; nf < 4; nf++){
      #pragma unroll
      for (int e = 0; e < 4; e++){
        float v = acc[mf][nf][e];
        int row = m0 + wr * 64 + mf * 16 + lr * 4 + e;
        int col = n0 + wc * 64 + nf * 16 + lc;
        if (!isR){
          int t = row >> 2, bb2 = row & 3;
          int s = col >> 10, rem = col & 1023;
          int h = rem >> 6, d = rem & 63;
          if (s == 0){
            if (t >= MLEN)
              qo[((size_t)(bb2 * NH + h) * QLEN + (t - MLEN)) * DH + d] = f2b(v);
          } else if (s == 1){
            ko[((size_t)(bb2 * NH + h) * KLEN + t) * DH + d] = f2b(v);    // k [bh][t][d]
          } else {
            vo[((size_t)(bb2 * NH + h) * DH + d) * KLEN + t] = f2b(v);    // v [bh][d][t]
          }
        } else {
          int h = col >> 6, d = col & 63;
          rh[((size_t)h * KLEN + row) * DH + d] = f2b(v);
        }
      }
    }
  }
}

// ---------------- output projection GEMM (bf16 C out, XCD-swizzled) ----------

__global__ __launch_bounds__(256, 4) void gemm3(
    const u16* __restrict__ A, const u16* __restrict__ Bt, int K,
    u16* __restrict__ o0)
{
  __shared__ u16 As[2][128 * 32];
  __shared__ u16 Bs[2][128 * 32];
  const int tid = threadIdx.x;
  const int lane = tid & 63, w = tid >> 6;
  const int wr = w >> 1, wc = w & 1;
  const int lr = lane >> 4, lc = lane & 15;
  const int bs = (blockIdx.x & 7) * 32 + (blockIdx.x >> 3);   // 256 % 8 == 0
  const int m0 = (bs >> 3) * 128, n0 = (bs & 7) * 128;

  f32x4 acc[4][4];
  #pragma unroll
  for (int i = 0; i < 4; i++)
    #pragma unroll
    for (int j = 0; j < 4; j++)
      acc[i][j] = (f32x4){0.f, 0.f, 0.f, 0.f};

  #pragma unroll
  for (int rnd = 0; rnd < 2; rnd++){
    int c = rnd * 256 + tid;
    int row = c >> 2, kc = c & 3;
    stage16((const char*)A + ((size_t)(m0 + row) * K + kc * 8) * 2,
            (char*)As + c * 16);
    stage16((const char*)Bt + ((size_t)(n0 + row) * K + kc * 8) * 2,
            (char*)Bs + c * 16);
  }

  const int NK = K >> 5;
  for (int it = 0; it < NK; ++it){
    const int cur = it & 1, nxt = cur ^ 1;
    if (it + 1 < NK){
      const int k0 = (it + 1) << 5;
      #pragma unroll
      for (int rnd = 0; rnd < 2; rnd++){
        int c = rnd * 256 + tid;
        int row = c >> 2, kc = c & 3;
        stage16((const char*)A + ((size_t)(m0 + row) * K + k0 + kc * 8) * 2,
                (char*)As + nxt * 8192 + c * 16);
        stage16((const char*)Bt + ((size_t)(n0 + row) * K + k0 + kc * 8) * 2,
                (char*)Bs + nxt * 8192 + c * 16);
      }
      asm volatile("s_waitcnt vmcnt(4)" ::: "memory");
    } else {
      asm volatile("s_waitcnt vmcnt(0)" ::: "memory");
    }
    __builtin_amdgcn_s_barrier();

    bf16x8 af[4], bfr[4];
    #pragma unroll
    for (int mf = 0; mf < 4; mf++)
      af[mf] = *(const bf16x8*)((const char*)As + cur * 8192 +
                                (wr * 64 + mf * 16 + lc) * 64 + lr * 16);
    #pragma unroll
    for (int nf = 0; nf < 4; nf++)
      bfr[nf] = *(const bf16x8*)((const char*)Bs + cur * 8192 +
                                 (wc * 64 + nf * 16 + lc) * 64 + lr * 16);
    #pragma unroll
    for (int mf = 0; mf < 4; mf++)
      #pragma unroll
      for (int nf = 0; nf < 4; nf++)
        acc[mf][nf] = MFMA16(af[mf], bfr[nf], acc[mf][nf]);
    __builtin_amdgcn_s_barrier();
  }

  #pragma unroll
  for (int mf = 0; mf < 4; mf++){
    #pragma unroll
    for (int nf = 0; nf < 4; nf++){
      #pragma unroll
      for (int e = 0; e < 4; e++){
        int row = m0 + wr * 64 + mf * 16 + lr * 4 + e;
        int col = n0 + wc * 64 + nf * 16 + lc;
        o0[(size_t)row * DM + col] = f2b(acc[mf][nf][e]);
      }
    }
  }
}

// ---------------- fused flash attention (r15 structure + ptr-inc staging) ----
// Swapped-operand + T15 1-deep softmax pipeline + lane-local defer-max.
// Staging addresses are precomputed per-thread offsets + per-iter cursor
// increments (constant strides); the R-band tail clamp is dropped: overshoot
// lands in the adjacent av workspace buffer (in-bounds) and only feeds
// positions that the last-tile mask overwrites with -1e30.

__global__ __launch_bounds__(256, 2) void attn_k(
    const u16* __restrict__ qB,  const u16* __restrict__ kB,
    const u16* __restrict__ vB,  const u16* __restrict__ rhB,
    const float* __restrict__ rwb, const float* __restrict__ rrb,
    u16* __restrict__ av)
{
  __shared__ u16 Kt[2][64 * 64];      // [j][d] swizzled     16 KB
  __shared__ u16 Rb[2][64 * 64];      // band [t'][d] swz    16 KB
  __shared__ u16 Vt[3][64 * 64];      // [d][j] swizzled     24 KB
  __shared__ u16 Pbd[3][64 * 64];     // BD [q][t'] row-XOR  24 KB   total 80 KB

  const int tid = threadIdx.x, lane = tid & 63, w = tid >> 6;
  const int lr = lane >> 4, lc = lane & 15;

  // XCD remap (bid%8 = XCD, i fastest) + snake pairing for tail balance
  const int bid = blockIdx.x;
  const int nid = (bid & 7) * 128 + (bid >> 3);
  const int tt = nid & 15;
  const int iblk = (tt & 1) ? (15 - (tt >> 1)) : (tt >> 1);
  const int i0 = iblk * 64;
  const int h  = (nid >> 4) & 15;
  const int b  = nid >> 8;
  const size_t bh = (size_t)b * NH + h;

  const float SCL = 0.18033688011112042f;   // 0.125 * log2(e) -> exp2 domain

  // Q fragments with biases, pre-scaled (q-row = i0 + w*16 + lc)
  bf16x8 qw_[2], qr_[2];
  #pragma unroll
  for (int ks = 0; ks < 2; ks++){
    bf16x8 qv = *(const bf16x8*)(qB + (bh * QLEN + i0 + w * 16 + lc) * DH + ks * 32 + lr * 8);
    #pragma unroll
    for (int e2 = 0; e2 < 8; e2++){
      int d = ks * 32 + lr * 8 + e2;
      float q32 = b2f((u16)qv[e2]);
      qw_[ks][e2] = (short)f2bn((q32 + rwb[h * DH + d]) * SCL);
      qr_[ks][e2] = (short)f2bn((q32 + rrb[h * DH + d]) * SCL);
    }
  }

  bf16x8 onesv;
  #pragma unroll
  for (int e2 = 0; e2 < 8; e2++) onesv[e2] = (short)0x3F80;

  // jt-invariant sheared-pickup metadata (q-row il = w*16+lc per lane)
  const int il = w * 16 + lc;
  int pbo[4][4]; bool sel[4][4], mskc[4][4];
  #pragma unroll
  for (int n = 0; n < 4; n++)
    #pragma unroll
    for (int e = 0; e < 4; e++){
      int dd = n * 16 + lr * 4 + e - il;
      pbo[n][e] = il * 128 + ((2 * (dd & 63)) ^ ((il & 7) << 4));
      sel[n][e] = dd < 0;
      mskc[n][e] = dd > 0;
    }

  f32x4 O[4];
  f32x4 sp[4];                       // prev-tile scores (pipeline register)
  float mx = -3.0e38f, sm = 0.f;
  #pragma unroll
  for (int df = 0; df < 4; df++) O[df] = (f32x4){0.f, 0.f, 0.f, 0.f};

  const char* kgb = (const char*)(kB + bh * (size_t)KLEN * DH);
  const char* vgb = (const char*)(vB + bh * (size_t)KLEN * DH);   // [DH][KLEN]
  const char* rgb = (const char*)(rhB + (size_t)h * KLEN * DH);

  const int jtiles = (i0 >> 6) + 17;

  // per-thread staging offsets (iteration-invariant)
  int kgoff[2], vgoff[2], ldo[2];
  #pragma unroll
  for (int rnd = 0; rnd < 2; rnd++){
    int c = rnd * 256 + tid;
    int row = c >> 3;
    int ch = (c & 7) ^ ((row ^ (row >> 3)) & 7);
    kgoff[rnd] = row * 128 + ch * 16;    // also used for R (same geometry)
    vgoff[rnd] = row * 4096 + ch * 16;
    ldo[rnd]   = c * 16;
  }
  // staging cursors: first main-loop stage is tile jt=1
  const char* kcur = kgb + 64 * 128;
  const char* vcur = vgb + 64 * 2;
  const char* rcur = rgb + (size_t)(1023 - i0 + 64) * 128;   // unclamped (safe)

  // softmax + PV for tile (jt2-1); pc/pp/Vt index = (jt2+2)%3
  auto softmax_pv = [&](int jt2, bool domask){
    const int pc = (jt2 + 2) % 3, pp = (jt2 + 1) % 3;
    const char* pbC = (const char*)&Pbd[pc][0];
    const char* pbP = (const char*)&Pbd[pp][0];
    float mm[4];
    #pragma unroll
    for (int n = 0; n < 4; n++){
      #pragma unroll
      for (int e = 0; e < 4; e++){
        u16 bd = *(const u16*)((sel[n][e] ? pbP : pbC) + pbo[n][e]);
        float x = sp[n][e] + b2f(bd);
        if (domask && mskc[n][e]) x = -1.0e30f;
        sp[n][e] = x;
      }
      mm[n] = fmaxf(fmaxf(sp[n][0], sp[n][1]), fmaxf(sp[n][2], sp[n][3]));
    }
    float tl = fmaxf(fmaxf(mm[0], mm[1]), fmaxf(mm[2], mm[3]));   // lane-local
    if (__any(tl > mx + 8.0f)){
      float tm = tl;
      tm = fmaxf(tm, __shfl_xor(tm, 16));
      tm = fmaxf(tm, __shfl_xor(tm, 32));
      float nmv = fmaxf(mx, tm);
      float fc = __builtin_amdgcn_exp2f(mx - nmv);
      mx = nmv;
      sm *= fc;
      #pragma unroll
      for (int df = 0; df < 4; df++)
        #pragma unroll
        for (int e = 0; e < 4; e++) O[df][e] *= fc;
    }
    #pragma unroll
    for (int n = 0; n < 4; n++)
      #pragma unroll
      for (int e = 0; e < 4; e++)
        sp[n][e] = __builtin_amdgcn_exp2f(sp[n][e] - mx);   // <= 2^8

    u32 c0 = pk2(sp[0][0], sp[0][1]), c1 = pk2(sp[0][2], sp[0][3]);
    u32 c2 = pk2(sp[1][0], sp[1][1]), c3 = pk2(sp[1][2], sp[1][3]);
    u32 c4 = pk2(sp[2][0], sp[2][1]), c5 = pk2(sp[2][2], sp[2][3]);
    u32 c6 = pk2(sp[3][0], sp[3][1]), c7 = pk2(sp[3][2], sp[3][3]);
    u32x2 uA = pl32sw(c0, c2); u32x2 vA = pl16sw(uA.x, uA.y);
    u32x2 uB = pl32sw(c1, c3); u32x2 vB2 = pl16sw(uB.x, uB.y);
    u32x2 uC = pl32sw(c4, c6); u32x2 vC = pl16sw(uC.x, uC.y);
    u32x2 uD = pl32sw(c5, c7); u32x2 vD = pl16sw(uD.x, uD.y);
    u32x4 t0; t0.x = vA.x; t0.y = vB2.x; t0.z = vA.y; t0.w = vB2.y;
    u32x4 t1; t1.x = vC.x; t1.y = vD.x; t1.z = vC.y; t1.w = vD.y;
    bf16x8 pb0 = __builtin_bit_cast(bf16x8, t0);
    bf16x8 pb1 = __builtin_bit_cast(bf16x8, t1);

    __builtin_amdgcn_s_setprio(1);
    f32x4 zs = (f32x4){0.f, 0.f, 0.f, 0.f};
    zs = MFMA16(onesv, pb0, zs);
    zs = MFMA16(onesv, pb1, zs);
    #pragma unroll
    for (int df = 0; df < 4; df++){
      bf16x8 v0 = *(const bf16x8*)((const char*)&Vt[pc][0] + swz(df * 16 + lc, lr * 16));
      bf16x8 v1 = *(const bf16x8*)((const char*)&Vt[pc][0] + swz(df * 16 + lc, 64 + lr * 16));
      O[df] = MFMA16(v0, pb0, O[df]);
      O[df] = MFMA16(v1, pb1, O[df]);
    }
    __builtin_amdgcn_s_setprio(0);
    sm += zs[0];
  };

  // ---- prologue: prev band BD -> Pbd[2]; stage tile0 (clamped, one-time) ----
  {
    int tbp = 959 - i0;
    #pragma unroll
    for (int rnd = 0; rnd < 2; rnd++){
      int c = rnd * 256 + tid;
      int row = c >> 3;
      int ch = (c & 7) ^ ((row ^ (row >> 3)) & 7);
      int t = tbp + row; t = t < 0 ? 0 : t;
      stage16(rgb + (size_t)t * 128 + ch * 16, (char*)&Rb[1][0] + c * 16);
    }
    asm volatile("s_waitcnt vmcnt(0)" ::: "memory");
    __builtin_amdgcn_s_barrier();
    #pragma unroll
    for (int rnd = 0; rnd < 2; rnd++){
      stage16(kgb + kgoff[rnd], (char*)&Kt[0][0] + ldo[rnd]);
      stage16(vgb + vgoff[rnd], (char*)&Vt[0][0] + ldo[rnd]);
      stage16(rgb + (size_t)(1023 - i0) * 128 + kgoff[rnd], (char*)&Rb[0][0] + ldo[rnd]);
    }
    // BD(-1) from Rb[1] -> Pbd[2]
    #pragma unroll
    for (int n2 = 0; n2 < 4; n2++){
      bf16x8 a0 = *(const bf16x8*)((const char*)&Rb[1][0] + swz(n2 * 16 + lc, lr * 16));
      bf16x8 a1 = *(const bf16x8*)((const char*)&Rb[1][0] + swz(n2 * 16 + lc, 64 + lr * 16));
      f32x4 z = (f32x4){0.f, 0.f, 0.f, 0.f};
      z = MFMA16(a0, qr_[0], z);
      z = MFMA16(a1, qr_[1], z);
      int row = w * 16 + lc;
      uint2 pr; pr.x = pk2(z[0], z[1]); pr.y = pk2(z[2], z[3]);
      *(uint2*)((char*)&Pbd[2][0] + row * 128 + ((n2 * 32 + lr * 8) ^ ((row & 7) << 4))) = pr;
    }
  }

  for (int jt2 = 0; jt2 < jtiles; jt2++){
    asm volatile("s_waitcnt vmcnt(0)" ::: "memory");
    __builtin_amdgcn_s_barrier();
    // issue next-tile stages via cursor increments
    if (jt2 + 1 < jtiles){
      char* kd = (char*)&Kt[(jt2 + 1) & 1][0];
      char* vd = (char*)&Vt[(jt2 + 1) % 3][0];
      char* rd = (char*)&Rb[(jt2 + 1) & 1][0];
      #pragma unroll
      for (int rnd = 0; rnd < 2; rnd++){
        stage16(kcur + kgoff[rnd], kd + ldo[rnd]);
        stage16(vcur + vgoff[rnd], vd + ldo[rnd]);
        stage16(rcur + kgoff[rnd], rd + ldo[rnd]);
      }
    }
    kcur += 64 * 128;
    vcur += 64 * 2;
    rcur += 64 * 128;

    // AC^T(jt2) = K (q + rwb)^T  and  BD(jt2) -> Pbd[jt2%3]
    f32x4 scur[4];
    __builtin_amdgcn_s_setprio(1);
    #pragma unroll
    for (int n = 0; n < 4; n++){
      bf16x8 k0f = *(const bf16x8*)((const char*)&Kt[jt2 & 1][0] + swz(n * 16 + lc, lr * 16));
      bf16x8 k1f = *(const bf16x8*)((const char*)&Kt[jt2 & 1][0] + swz(n * 16 + lc, 64 + lr * 16));
      f32x4 z = (f32x4){0.f, 0.f, 0.f, 0.f};
      z = MFMA16(k0f, qw_[0], z);
      z = MFMA16(k1f, qw_[1], z);
      scur[n] = z;
    }
    #pragma unroll
    for (int n2 = 0; n2 < 4; n2++){
      bf16x8 a0 = *(const bf16x8*)((const char*)&Rb[jt2 & 1][0] + swz(n2 * 16 + lc, lr * 16));
      bf16x8 a1 = *(const bf16x8*)((const char*)&Rb[jt2 & 1][0] + swz(n2 * 16 + lc, 64 + lr * 16));
      f32x4 z = (f32x4){0.f, 0.f, 0.f, 0.f};
      z = MFMA16(a0, qr_[0], z);
      z = MFMA16(a1, qr_[1], z);
      int row = w * 16 + lc;
      uint2 pr; pr.x = pk2(z[0], z[1]); pr.y = pk2(z[2], z[3]);
      *(uint2*)((char*)&Pbd[jt2 % 3][0] + row * 128 + ((n2 * 32 + lr * 8) ^ ((row & 7) << 4))) = pr;
    }
    __builtin_amdgcn_s_setprio(0);

    // softmax + PV for tile jt2-1 (independent of the MFMAs just issued)
    if (jt2 > 0) softmax_pv(jt2, false);

    #pragma unroll
    for (int n = 0; n < 4; n++) sp[n] = scur[n];
  }

  // epilogue: softmax + PV for the last tile (the only masked one)
  softmax_pv(jtiles, true);

  asm volatile("s_waitcnt vmcnt(0)" ::: "memory");

  // O^T[d = df*16+lr*4+e][q = lc]: packed dwordx2 stores
  {
    float is = 1.0f / sm;
    const int i = i0 + w * 16 + lc;
    u16* dst = av + (size_t)(i * BSZ + b) * DM + h * DH + lr * 4;
    #pragma unroll
    for (int df = 0; df < 4; df++){
      uint2 pr;
      pr.x = pk2(O[df][0] * is, O[df][1] * is);
      pr.y = pk2(O[df][2] * is, O[df][3] * is);
      *(uint2*)(dst + df * 16) = pr;
    }
  }
}

// ---------------- residual + LayerNorm (bf16 ao input) ----------------

__global__ __launch_bounds__(256) void ln_k(const float* __restrict__ w,
                                            const u16* __restrict__ ao,
                                            const float* __restrict__ gam,
                                            const float* __restrict__ bet,
                                            float* __restrict__ out){
  __shared__ float red[8];
  const int rw = blockIdx.x, t = threadIdx.x, lane = t & 63, wv = t >> 6;
  const float* wr_ = w + (size_t)rw * DM;
  const u16* ar_ = ao + (size_t)rw * DM;
  float x[4];
  float s = 0.f, ss = 0.f;
  #pragma unroll
  for (int k2 = 0; k2 < 4; k2++){
    int c = t + k2 * 256;
    float xv = wr_[c] + b2f(ar_[c]);
    x[k2] = xv; s += xv; ss += xv * xv;
  }
  #pragma unroll
  for (int m2 = 1; m2 < 64; m2 <<= 1){ s += __shfl_xor(s, m2); ss += __shfl_xor(ss, m2); }
  if (lane == 0){ red[wv] = s; red[4 + wv] = ss; }
  __syncthreads();
  s  = red[0] + red[1] + red[2] + red[3];
  ss = red[4] + red[5] + red[6] + red[7];
  float mu = s * (1.f / DM);
  float var = ss * (1.f / DM) - mu * mu;
  float rs = rsqrtf(var + 1e-5f);
  #pragma unroll
  for (int k2 = 0; k2 < 4; k2++){
    int c = t + k2 * 256;
    out[(size_t)rw * DM + c] = (x[k2] - mu) * rs * gam[c] + bet[c];
  }
}

// ---------------- launch ----------------

extern "C" void kernel_launch(void* const* d_in, const int* in_sizes, int n_in,
                              void* d_out, int out_size, void* d_ws, size_t ws_size,
                              hipStream_t stream)
{
  (void)in_sizes; (void)n_in; (void)out_size; (void)ws_size;
  const float* w    = (const float*)d_in[0];
  const float* r    = (const float*)d_in[1];
  const float* mems = (const float*)d_in[2];
  const float* Wqkv = (const float*)d_in[3];
  const float* Wr   = (const float*)d_in[4];
  const float* Wo   = (const float*)d_in[5];
  const float* rwb  = (const float*)d_in[6];
  const float* rrb  = (const float*)d_in[7];
  const float* gam  = (const float*)d_in[8];
  const float* bet  = (const float*)d_in[9];
  float* out = (float*)d_out;

  char* ws = (char*)d_ws;
  size_t off = 0;
  auto alloc = [&](size_t n){ char* p = ws + off; off += (n + 255) & ~(size_t)255; return p; };
  u16* catB  = (u16*)alloc((size_t)KLEN * BSZ * DM * 2);
  u16* rB    = (u16*)alloc((size_t)KLEN * DM * 2);
  u16* WqkvT = (u16*)alloc((size_t)3 * DM * DM * 2);
  u16* WrT   = (u16*)alloc((size_t)DM * DM * 2);
  u16* WoT   = (u16*)alloc((size_t)DM * DM * 2);
  u16* qBuf  = (u16*)alloc((size_t)BSZ * NH * QLEN * DH * 2);
  u16* kBp   = (u16*)alloc((size_t)BSZ * NH * KLEN * DH * 2);
  u16* vBp   = (u16*)alloc((size_t)BSZ * NH * KLEN * DH * 2);   // d-major
  u16* rhB   = (u16*)alloc((size_t)NH * KLEN * DH * 2);
  u16* av    = (u16*)alloc((size_t)QLEN * BSZ * DM * 2);        // rh tail overshoot lands here (masked)
  u16* ao    = (u16*)alloc((size_t)QLEN * BSZ * DM * 2);

  // conversions + weight transposes in one launch
  prep_k<<<dim3(15360), 256, 0, stream>>>(mems, w, r, Wqkv, WqkvT, Wr, WrT, Wo, WoT, catB, rB);

  // QKV + R projections merged (R blocks tail-fill), XCD-swizzled
  gemm01<<<dim3(1664), 256, 0, stream>>>(catB, WqkvT, rB, WrT, qBuf, kBp, vBp, rhB);

  // fused attention: 1024 blocks x 256 threads (2 blocks/CU, 80 KB LDS each)
  attn_k<<<dim3(1024), 256, 0, stream>>>(qBuf, kBp, vBp, rhB, rwb, rrb, av);

  // output projection: [4096,1024] x [1024,1024] (bf16 C, XCD-swizzled)
  gemm3<<<dim3(256), 256, 0, stream>>>(av, WoT, DM, ao);
  ln_k<<<dim3(4096), 256, 0, stream>>>(w, ao, gam, bet, out);
}

// Round 19
// 253.551 us; speedup vs baseline: 1.0006x; 1.0006x over previous
//
#include <hip/hip_runtime.h>
#include <hip/hip_bf16.h>
#include <stdint.h>

#define QLEN 1024
#define MLEN 1024
#define KLEN 2048
#define BSZ 4
#define NH 16
#define DH 64
#define DM 1024

typedef __attribute__((ext_vector_type(8))) short bf16x8;
typedef __attribute__((ext_vector_type(4))) float f32x4;
typedef __attribute__((ext_vector_type(4))) unsigned int u32x4;
typedef __attribute__((ext_vector_type(2))) unsigned int u32x2;
typedef unsigned short u16;
typedef unsigned int u32;

typedef unsigned int __attribute__((address_space(1))) gu32;
typedef unsigned int __attribute__((address_space(3))) lu32;

__device__ __forceinline__ void stage16(const void* g, void* l){
  __builtin_amdgcn_global_load_lds((const gu32*)g, (lu32*)l, 16, 0, 0);
}

__device__ __forceinline__ u16 f2b(float f){
  u32 u = __builtin_bit_cast(u32, f);
  u32 r = (u + 0x7FFFu + ((u >> 16) & 1u)) >> 16;
  return (u16)r;
}
__device__ __forceinline__ float b2f(u16 v){
  u32 u = ((u32)v) << 16;
  return __builtin_bit_cast(float, u);
}
__device__ __forceinline__ u16 f2bn(float f){
  __hip_bfloat16 h = __float2bfloat16(f);
  u16 r; __builtin_memcpy(&r, &h, 2); return r;
}
__device__ __forceinline__ u32 pk2(float a, float b){
  float2 t; t.x = a; t.y = b;
  __hip_bfloat162 h = __float22bfloat162_rn(t);
  u32 r; __builtin_memcpy(&r, &h, 4); return r;
}

// XOR swizzle for [rows][64]bf16 tiles (128B rows)
__device__ __forceinline__ int swz(int row, int byteoff){
  return (row << 7) + (byteoff ^ (((row ^ (row >> 3)) & 7) << 4));
}

// 2x2 block-transpose swaps between two registers.
__device__ __forceinline__ u32x2 pl32sw(u32 a, u32 b){
#if __has_builtin(__builtin_amdgcn_permlane32_swap)
  auto t = __builtin_amdgcn_permlane32_swap(a, b, false, false);
  u32x2 o; __builtin_memcpy(&o, &t, 8); return o;
#else
  int sa = __shfl_xor((int)a, 32), sb = __shfl_xor((int)b, 32);
  int l = threadIdx.x & 63;
  u32x2 o;
  o.x = (l & 32) ? (u32)sb : a;
  o.y = (l & 32) ? b : (u32)sa;
  return o;
#endif
}
__device__ __forceinline__ u32x2 pl16sw(u32 a, u32 b){
#if __has_builtin(__builtin_amdgcn_permlane16_swap)
  auto t = __builtin_amdgcn_permlane16_swap(a, b, false, false);
  u32x2 o; __builtin_memcpy(&o, &t, 8); return o;
#else
  u32 sb = (u32)__builtin_amdgcn_ds_swizzle((int)b, 0x401F);
  u32 sa = (u32)__builtin_amdgcn_ds_swizzle((int)a, 0x401F);
  int l = threadIdx.x & 63;
  u32x2 o;
  o.x = (l & 16) ? sb : a;
  o.y = (l & 16) ? b : sa;
  return o;
#endif
}

#define MFMA16(a, b, c) __builtin_amdgcn_mfma_f32_16x16x32_bf16(a, b, c, 0, 0, 0)

// ---------------- prep: conversions + weight transposes, one launch ----------

__global__ __launch_bounds__(256) void prep_k(
    const float* __restrict__ mems, const float* __restrict__ w,
    const float* __restrict__ r,
    const float* __restrict__ s0, u16* __restrict__ d0,
    const float* __restrict__ s1, u16* __restrict__ d1,
    const float* __restrict__ s2, u16* __restrict__ d2,
    u16* __restrict__ catB, u16* __restrict__ rB)
{
  __shared__ float tile[32][33];
  int bx = blockIdx.x;
  if (bx < 8192){
    int idx = bx * 256 + threadIdx.x;
    const int memf4 = MLEN * BSZ * DM / 4;
    float4 v = (idx < memf4) ? ((const float4*)mems)[idx]
                             : ((const float4*)w)[idx - memf4];
    ushort4 o;
    o.x = f2b(v.x); o.y = f2b(v.y); o.z = f2b(v.z); o.w = f2b(v.w);
    ((ushort4*)catB)[idx] = o;
    return;
  }
  if (bx < 10240){
    int idx = (bx - 8192) * 256 + threadIdx.x;
    float4 v = ((const float4*)r)[idx];
    ushort4 o;
    o.x = f2b(v.x); o.y = f2b(v.y); o.z = f2b(v.z); o.w = f2b(v.w);
    ((ushort4*)rB)[idx] = o;
    return;
  }
  int t = bx - 10240;              // 0..5119
  int sub = t % 160, r0 = (t / 160) * 32;
  const float* src; u16* dst; int C, c0;
  if (sub < 96){ src = s0; dst = d0; C = 3 * DM; c0 = sub * 32; }
  else if (sub < 128){ src = s1; dst = d1; C = DM; c0 = (sub - 96) * 32; }
  else { src = s2; dst = d2; C = DM; c0 = (sub - 128) * 32; }
  int tx = threadIdx.x & 31, ty = threadIdx.x >> 5;
  #pragma unroll
  for (int rr = ty; rr < 32; rr += 8)
    tile[rr][tx] = src[(size_t)(r0 + rr) * C + c0 + tx];
  __syncthreads();
  #pragma unroll
  for (int rr = ty; rr < 32; rr += 8)
    dst[(size_t)(c0 + rr) * DM + r0 + tx] = f2b(tile[tx][rr]);
}

// ---------------- merged QKV + R projection GEMM (128x128, BK=32, 2-phase) ----
// XCD-swizzled (1664 % 8 == 0, cpx = 208): A-panels L2-local per XCD.

__global__ __launch_bounds__(256, 4) void gemm01(
    const u16* __restrict__ catB, const u16* __restrict__ WqkvT,
    const u16* __restrict__ rB,   const u16* __restrict__ WrT,
    u16* __restrict__ qo, u16* __restrict__ ko, u16* __restrict__ vo,
    u16* __restrict__ rh)
{
  __shared__ u16 As[2][128 * 32];
  __shared__ u16 Bs[2][128 * 32];
  const int tid = threadIdx.x;
  const int lane = tid & 63, w = tid >> 6;
  const int wr = w >> 1, wc = w & 1;
  const int lr = lane >> 4, lc = lane & 15;
  const int bx = blockIdx.x;
  const int bs = (bx & 7) * 208 + (bx >> 3);   // bijective XCD swizzle
  const bool isR = bs >= 1536;
  const u16* A  = isR ? rB : catB;
  const u16* Bt = isR ? WrT : WqkvT;
  const int bb  = isR ? bs - 1536 : bs;
  const int nbx = isR ? 8 : 24;
  const int m0 = (bb / nbx) * 128, n0 = (bb % nbx) * 128;
  const int K = DM;

  f32x4 acc[4][4];
  #pragma unroll
  for (int i = 0; i < 4; i++)
    #pragma unroll
    for (int j = 0; j < 4; j++)
      acc[i][j] = (f32x4){0.f, 0.f, 0.f, 0.f};

  #pragma unroll
  for (int rnd = 0; rnd < 2; rnd++){
    int c = rnd * 256 + tid;
    int row = c >> 2, kc = c & 3;
    stage16((const char*)A + ((size_t)(m0 + row) * K + kc * 8) * 2,
            (char*)As + c * 16);
    stage16((const char*)Bt + ((size_t)(n0 + row) * K + kc * 8) * 2,
            (char*)Bs + c * 16);
  }

  const int NK = K >> 5;
  for (int it = 0; it < NK; ++it){
    const int cur = it & 1, nxt = cur ^ 1;
    if (it + 1 < NK){
      const int k0 = (it + 1) << 5;
      #pragma unroll
      for (int rnd = 0; rnd < 2; rnd++){
        int c = rnd * 256 + tid;
        int row = c >> 2, kc = c & 3;
        stage16((const char*)A + ((size_t)(m0 + row) * K + k0 + kc * 8) * 2,
                (char*)As + nxt * 8192 + c * 16);
        stage16((const char*)Bt + ((size_t)(n0 + row) * K + k0 + kc * 8) * 2,
                (char*)Bs + nxt * 8192 + c * 16);
      }
      asm volatile("s_waitcnt vmcnt(4)" ::: "memory");
    } else {
      asm volatile("s_waitcnt vmcnt(0)" ::: "memory");
    }
    __builtin_amdgcn_s_barrier();

    bf16x8 af[4], bfr[4];
    #pragma unroll
    for (int mf = 0; mf < 4; mf++)
      af[mf] = *(const bf16x8*)((const char*)As + cur * 8192 +
                                (wr * 64 + mf * 16 + lc) * 64 + lr * 16);
    #pragma unroll
    for (int nf = 0; nf < 4; nf++)
      bfr[nf] = *(const bf16x8*)((const char*)Bs + cur * 8192 +
                                 (wc * 64 + nf * 16 + lc) * 64 + lr * 16);
    #pragma unroll
    for (int mf = 0; mf < 4; mf++)
      #pragma unroll
      for (int nf = 0; nf < 4; nf++)
        acc[mf][nf] = MFMA16(af[mf], bfr[nf], acc[mf][nf]);
    __builtin_amdgcn_s_barrier();
  }

  #pragma unroll
  for (int mf = 0; mf < 4; mf++){
    #pragma unroll
    for (int nf = 0; nf < 4; nf++){
      #pragma unroll
      for (int e = 0; e < 4; e++){
        float v = acc[mf][nf][e];
        int row = m0 + wr * 64 + mf * 16 + lr * 4 + e;
        int col = n0 + wc * 64 + nf * 16 + lc;
        if (!isR){
          int t = row >> 2, bb2 = row & 3;
          int s = col >> 10, rem = col & 1023;
          int h = rem >> 6, d = rem & 63;
          if (s == 0){
            if (t >= MLEN)
              qo[((size_t)(bb2 * NH + h) * QLEN + (t - MLEN)) * DH + d] = f2b(v);
          } else if (s == 1){
            ko[((size_t)(bb2 * NH + h) * KLEN + t) * DH + d] = f2b(v);    // k [bh][t][d]
          } else {
            vo[((size_t)(bb2 * NH + h) * DH + d) * KLEN + t] = f2b(v);    // v [bh][d][t]
          }
        } else {
          int h = col >> 6, d = col & 63;
          rh[((size_t)h * KLEN + row) * DH + d] = f2b(v);
        }
      }
    }
  }
}

// ---------------- output projection GEMM (bf16 C out, XCD-swizzled) ----------

__global__ __launch_bounds__(256, 4) void gemm3(
    const u16* __restrict__ A, const u16* __restrict__ Bt, int K,
    u16* __restrict__ o0)
{
  __shared__ u16 As[2][128 * 32];
  __shared__ u16 Bs[2][128 * 32];
  const int tid = threadIdx.x;
  const int lane = tid & 63, w = tid >> 6;
  const int wr = w >> 1, wc = w & 1;
  const int lr = lane >> 4, lc = lane & 15;
  const int bs = (blockIdx.x & 7) * 32 + (blockIdx.x >> 3);   // 256 % 8 == 0
  const int m0 = (bs >> 3) * 128, n0 = (bs & 7) * 128;

  f32x4 acc[4][4];
  #pragma unroll
  for (int i = 0; i < 4; i++)
    #pragma unroll
    for (int j = 0; j < 4; j++)
      acc[i][j] = (f32x4){0.f, 0.f, 0.f, 0.f};

  #pragma unroll
  for (int rnd = 0; rnd < 2; rnd++){
    int c = rnd * 256 + tid;
    int row = c >> 2, kc = c & 3;
    stage16((const char*)A + ((size_t)(m0 + row) * K + kc * 8) * 2,
            (char*)As + c * 16);
    stage16((const char*)Bt + ((size_t)(n0 + row) * K + kc * 8) * 2,
            (char*)Bs + c * 16);
  }

  const int NK = K >> 5;
  for (int it = 0; it < NK; ++it){
    const int cur = it & 1, nxt = cur ^ 1;
    if (it + 1 < NK){
      const int k0 = (it + 1) << 5;
      #pragma unroll
      for (int rnd = 0; rnd < 2; rnd++){
        int c = rnd * 256 + tid;
        int row = c >> 2, kc = c & 3;
        stage16((const char*)A + ((size_t)(m0 + row) * K + k0 + kc * 8) * 2,
                (char*)As + nxt * 8192 + c * 16);
        stage16((const char*)Bt + ((size_t)(n0 + row) * K + k0 + kc * 8) * 2,
                (char*)Bs + nxt * 8192 + c * 16);
      }
      asm volatile("s_waitcnt vmcnt(4)" ::: "memory");
    } else {
      asm volatile("s_waitcnt vmcnt(0)" ::: "memory");
    }
    __builtin_amdgcn_s_barrier();

    bf16x8 af[4], bfr[4];
    #pragma unroll
    for (int mf = 0; mf < 4; mf++)
      af[mf] = *(const bf16x8*)((const char*)As + cur * 8192 +
                                (wr * 64 + mf * 16 + lc) * 64 + lr * 16);
    #pragma unroll
    for (int nf = 0; nf < 4; nf++)
      bfr[nf] = *(const bf16x8*)((const char*)Bs + cur * 8192 +
                                 (wc * 64 + nf * 16 + lc) * 64 + lr * 16);
    #pragma unroll
    for (int mf = 0; mf < 4; mf++)
      #pragma unroll
      for (int nf = 0; nf < 4; nf++)
        acc[mf][nf] = MFMA16(af[mf], bfr[nf], acc[mf][nf]);
    __builtin_amdgcn_s_barrier();
  }

  #pragma unroll
  for (int mf = 0; mf < 4; mf++){
    #pragma unroll
    for (int nf = 0; nf < 4; nf++){
      #pragma unroll
      for (int e = 0; e < 4; e++){
        int row = m0 + wr * 64 + mf * 16 + lr * 4 + e;
        int col = n0 + wc * 64 + nf * 16 + lc;
        o0[(size_t)row * DM + col] = f2b(acc[mf][nf][e]);
      }
    }
  }
}

// ---------------- fused flash attention (r15 structure + ptr-inc staging) ----

__global__ __launch_bounds__(256, 2) void attn_k(
    const u16* __restrict__ qB,  const u16* __restrict__ kB,
    const u16* __restrict__ vB,  const u16* __restrict__ rhB,
    const float* __restrict__ rwb, const float* __restrict__ rrb,
    u16* __restrict__ av)
{
  __shared__ u16 Kt[2][64 * 64];      // [j][d] swizzled     16 KB
  __shared__ u16 Rb[2][64 * 64];      // band [t'][d] swz    16 KB
  __shared__ u16 Vt[3][64 * 64];      // [d][j] swizzled     24 KB
  __shared__ u16 Pbd[3][64 * 64];     // BD [q][t'] row-XOR  24 KB   total 80 KB

  const int tid = threadIdx.x, lane = tid & 63, w = tid >> 6;
  const int lr = lane >> 4, lc = lane & 15;

  const int bid = blockIdx.x;
  const int nid = (bid & 7) * 128 + (bid >> 3);
  const int tt = nid & 15;
  const int iblk = (tt & 1) ? (15 - (tt >> 1)) : (tt >> 1);
  const int i0 = iblk * 64;
  const int h  = (nid >> 4) & 15;
  const int b  = nid >> 8;
  const size_t bh = (size_t)b * NH + h;

  const float SCL = 0.18033688011112042f;   // 0.125 * log2(e) -> exp2 domain

  bf16x8 qw_[2], qr_[2];
  #pragma unroll
  for (int ks = 0; ks < 2; ks++){
    bf16x8 qv = *(const bf16x8*)(qB + (bh * QLEN + i0 + w * 16 + lc) * DH + ks * 32 + lr * 8);
    #pragma unroll
    for (int e2 = 0; e2 < 8; e2++){
      int d = ks * 32 + lr * 8 + e2;
      float q32 = b2f((u16)qv[e2]);
      qw_[ks][e2] = (short)f2bn((q32 + rwb[h * DH + d]) * SCL);
      qr_[ks][e2] = (short)f2bn((q32 + rrb[h * DH + d]) * SCL);
    }
  }

  bf16x8 onesv;
  #pragma unroll
  for (int e2 = 0; e2 < 8; e2++) onesv[e2] = (short)0x3F80;

  const int il = w * 16 + lc;
  int pbo[4][4]; bool sel[4][4], mskc[4][4];
  #pragma unroll
  for (int n = 0; n < 4; n++)
    #pragma unroll
    for (int e = 0; e < 4; e++){
      int dd = n * 16 + lr * 4 + e - il;
      pbo[n][e] = il * 128 + ((2 * (dd & 63)) ^ ((il & 7) << 4));
      sel[n][e] = dd < 0;
      mskc[n][e] = dd > 0;
    }

  f32x4 O[4];
  f32x4 sp[4];
  float mx = -3.0e38f, sm = 0.f;
  #pragma unroll
  for (int df = 0; df < 4; df++) O[df] = (f32x4){0.f, 0.f, 0.f, 0.f};

  const char* kgb = (const char*)(kB + bh * (size_t)KLEN * DH);
  const char* vgb = (const char*)(vB + bh * (size_t)KLEN * DH);   // [DH][KLEN]
  const char* rgb = (const char*)(rhB + (size_t)h * KLEN * DH);

  const int jtiles = (i0 >> 6) + 17;

  int kgoff[2], vgoff[2], ldo[2];
  #pragma unroll
  for (int rnd = 0; rnd < 2; rnd++){
    int c = rnd * 256 + tid;
    int row = c >> 3;
    int ch = (c & 7) ^ ((row ^ (row >> 3)) & 7);
    kgoff[rnd] = row * 128 + ch * 16;
    vgoff[rnd] = row * 4096 + ch * 16;
    ldo[rnd]   = c * 16;
  }
  const char* kcur = kgb + 64 * 128;
  const char* vcur = vgb + 64 * 2;
  const char* rcur = rgb + (size_t)(1023 - i0 + 64) * 128;   // unclamped (safe)

  auto softmax_pv = [&](int jt2, bool domask){
    const int pc = (jt2 + 2) % 3, pp = (jt2 + 1) % 3;
    const char* pbC = (const char*)&Pbd[pc][0];
    const char* pbP = (const char*)&Pbd[pp][0];
    float mm[4];
    #pragma unroll
    for (int n = 0; n < 4; n++){
      #pragma unroll
      for (int e = 0; e < 4; e++){
        u16 bd = *(const u16*)((sel[n][e] ? pbP : pbC) + pbo[n][e]);
        float x = sp[n][e] + b2f(bd);
        if (domask && mskc[n][e]) x = -1.0e30f;
        sp[n][e] = x;
      }
      mm[n] = fmaxf(fmaxf(sp[n][0], sp[n][1]), fmaxf(sp[n][2], sp[n][3]));
    }
    float tl = fmaxf(fmaxf(mm[0], mm[1]), fmaxf(mm[2], mm[3]));
    if (__any(tl > mx + 8.0f)){
      float tm = tl;
      tm = fmaxf(tm, __shfl_xor(tm, 16));
      tm = fmaxf(tm, __shfl_xor(tm, 32));
      float nmv = fmaxf(mx, tm);
      float fc = __builtin_amdgcn_exp2f(mx - nmv);
      mx = nmv;
      sm *= fc;
      #pragma unroll
      for (int df = 0; df < 4; df++)
        #pragma unroll
        for (int e = 0; e < 4; e++) O[df][e] *= fc;
    }
    #pragma unroll
    for (int n = 0; n < 4; n++)
      #pragma unroll
      for (int e = 0; e < 4; e++)
        sp[n][e] = __builtin_amdgcn_exp2f(sp[n][e] - mx);

    u32 c0 = pk2(sp[0][0], sp[0][1]), c1 = pk2(sp[0][2], sp[0][3]);
    u32 c2 = pk2(sp[1][0], sp[1][1]), c3 = pk2(sp[1][2], sp[1][3]);
    u32 c4 = pk2(sp[2][0], sp[2][1]), c5 = pk2(sp[2][2], sp[2][3]);
    u32 c6 = pk2(sp[3][0], sp[3][1]), c7 = pk2(sp[3][2], sp[3][3]);
    u32x2 uA = pl32sw(c0, c2); u32x2 vA = pl16sw(uA.x, uA.y);
    u32x2 uB = pl32sw(c1, c3); u32x2 vB2 = pl16sw(uB.x, uB.y);
    u32x2 uC = pl32sw(c4, c6); u32x2 vC = pl16sw(uC.x, uC.y);
    u32x2 uD = pl32sw(c5, c7); u32x2 vD = pl16sw(uD.x, uD.y);
    u32x4 t0; t0.x = vA.x; t0.y = vB2.x; t0.z = vA.y; t0.w = vB2.y;
    u32x4 t1; t1.x = vC.x; t1.y = vD.x; t1.z = vC.y; t1.w = vD.y;
    bf16x8 pb0 = __builtin_bit_cast(bf16x8, t0);
    bf16x8 pb1 = __builtin_bit_cast(bf16x8, t1);

    __builtin_amdgcn_s_setprio(1);
    f32x4 zs = (f32x4){0.f, 0.f, 0.f, 0.f};
    zs = MFMA16(onesv, pb0, zs);
    zs = MFMA16(onesv, pb1, zs);
    #pragma unroll
    for (int df = 0; df < 4; df++){
      bf16x8 v0 = *(const bf16x8*)((const char*)&Vt[pc][0] + swz(df * 16 + lc, lr * 16));
      bf16x8 v1 = *(const bf16x8*)((const char*)&Vt[pc][0] + swz(df * 16 + lc, 64 + lr * 16));
      O[df] = MFMA16(v0, pb0, O[df]);
      O[df] = MFMA16(v1, pb1, O[df]);
    }
    __builtin_amdgcn_s_setprio(0);
    sm += zs[0];
  };

  // ---- prologue: prev band BD -> Pbd[2]; stage tile0 (clamped, one-time) ----
  {
    int tbp = 959 - i0;
    #pragma unroll
    for (int rnd = 0; rnd < 2; rnd++){
      int c = rnd * 256 + tid;
      int row = c >> 3;
      int ch = (c & 7) ^ ((row ^ (row >> 3)) & 7);
      int t = tbp + row; t = t < 0 ? 0 : t;
      stage16(rgb + (size_t)t * 128 + ch * 16, (char*)&Rb[1][0] + c * 16);
    }
    asm volatile("s_waitcnt vmcnt(0)" ::: "memory");
    __builtin_amdgcn_s_barrier();
    #pragma unroll
    for (int rnd = 0; rnd < 2; rnd++){
      stage16(kgb + kgoff[rnd], (char*)&Kt[0][0] + ldo[rnd]);
      stage16(vgb + vgoff[rnd], (char*)&Vt[0][0] + ldo[rnd]);
      stage16(rgb + (size_t)(1023 - i0) * 128 + kgoff[rnd], (char*)&Rb[0][0] + ldo[rnd]);
    }
    #pragma unroll
    for (int n2 = 0; n2 < 4; n2++){
      bf16x8 a0 = *(const bf16x8*)((const char*)&Rb[1][0] + swz(n2 * 16 + lc, lr * 16));
      bf16x8 a1 = *(const bf16x8*)((const char*)&Rb[1][0] + swz(n2 * 16 + lc, 64 + lr * 16));
      f32x4 z = (f32x4){0.f, 0.f, 0.f, 0.f};
      z = MFMA16(a0, qr_[0], z);
      z = MFMA16(a1, qr_[1], z);
      int row = w * 16 + lc;
      uint2 pr; pr.x = pk2(z[0], z[1]); pr.y = pk2(z[2], z[3]);
      *(uint2*)((char*)&Pbd[2][0] + row * 128 + ((n2 * 32 + lr * 8) ^ ((row & 7) << 4))) = pr;
    }
  }

  for (int jt2 = 0; jt2 < jtiles; jt2++){
    asm volatile("s_waitcnt vmcnt(0)" ::: "memory");
    __builtin_amdgcn_s_barrier();
    if (jt2 + 1 < jtiles){
      char* kd = (char*)&Kt[(jt2 + 1) & 1][0];
      char* vd = (char*)&Vt[(jt2 + 1) % 3][0];
      char* rd = (char*)&Rb[(jt2 + 1) & 1][0];
      #pragma unroll
      for (int rnd = 0; rnd < 2; rnd++){
        stage16(kcur + kgoff[rnd], kd + ldo[rnd]);
        stage16(vcur + vgoff[rnd], vd + ldo[rnd]);
        stage16(rcur + kgoff[rnd], rd + ldo[rnd]);
      }
    }
    kcur += 64 * 128;
    vcur += 64 * 2;
    rcur += 64 * 128;

    f32x4 scur[4];
    __builtin_amdgcn_s_setprio(1);
    #pragma unroll
    for (int n = 0; n < 4; n++){
      bf16x8 k0f = *(const bf16x8*)((const char*)&Kt[jt2 & 1][0] + swz(n * 16 + lc, lr * 16));
      bf16x8 k1f = *(const bf16x8*)((const char*)&Kt[jt2 & 1][0] + swz(n * 16 + lc, 64 + lr * 16));
      f32x4 z = (f32x4){0.f, 0.f, 0.f, 0.f};
      z = MFMA16(k0f, qw_[0], z);
      z = MFMA16(k1f, qw_[1], z);
      scur[n] = z;
    }
    #pragma unroll
    for (int n2 = 0; n2 < 4; n2++){
      bf16x8 a0 = *(const bf16x8*)((const char*)&Rb[jt2 & 1][0] + swz(n2 * 16 + lc, lr * 16));
      bf16x8 a1 = *(const bf16x8*)((const char*)&Rb[jt2 & 1][0] + swz(n2 * 16 + lc, 64 + lr * 16));
      f32x4 z = (f32x4){0.f, 0.f, 0.f, 0.f};
      z = MFMA16(a0, qr_[0], z);
      z = MFMA16(a1, qr_[1], z);
      int row = w * 16 + lc;
      uint2 pr; pr.x = pk2(z[0], z[1]); pr.y = pk2(z[2], z[3]);
      *(uint2*)((char*)&Pbd[jt2 % 3][0] + row * 128 + ((n2 * 32 + lr * 8) ^ ((row & 7) << 4))) = pr;
    }
    __builtin_amdgcn_s_setprio(0);

    if (jt2 > 0) softmax_pv(jt2, false);

    #pragma unroll
    for (int n = 0; n < 4; n++) sp[n] = scur[n];
  }

  softmax_pv(jtiles, true);

  asm volatile("s_waitcnt vmcnt(0)" ::: "memory");

  {
    float is = 1.0f / sm;
    const int i = i0 + w * 16 + lc;
    u16* dst = av + (size_t)(i * BSZ + b) * DM + h * DH + lr * 4;
    #pragma unroll
    for (int df = 0; df < 4; df++){
      uint2 pr;
      pr.x = pk2(O[df][0] * is, O[df][1] * is);
      pr.y = pk2(O[df][2] * is, O[df][3] * is);
      *(uint2*)(dst + df * 16) = pr;
    }
  }
}

// ---------------- residual + LayerNorm (vectorized: float4/short4 per thread) -

__global__ __launch_bounds__(256) void ln_k(const float* __restrict__ w,
                                            const u16* __restrict__ ao,
                                            const float* __restrict__ gam,
                                            const float* __restrict__ bet,
                                            float* __restrict__ out){
  __shared__ float red[8];
  const int rw = blockIdx.x, t = threadIdx.x, lane = t & 63, wv = t >> 6;
  float4 wv4 = ((const float4*)(w + (size_t)rw * DM))[t];
  ushort4 av4 = ((const ushort4*)(ao + (size_t)rw * DM))[t];
  float x[4];
  x[0] = wv4.x + b2f(av4.x);
  x[1] = wv4.y + b2f(av4.y);
  x[2] = wv4.z + b2f(av4.z);
  x[3] = wv4.w + b2f(av4.w);
  float s = (x[0] + x[1]) + (x[2] + x[3]);
  float ss = (x[0] * x[0] + x[1] * x[1]) + (x[2] * x[2] + x[3] * x[3]);
  #pragma unroll
  for (int m2 = 1; m2 < 64; m2 <<= 1){ s += __shfl_xor(s, m2); ss += __shfl_xor(ss, m2); }
  if (lane == 0){ red[wv] = s; red[4 + wv] = ss; }
  __syncthreads();
  s  = red[0] + red[1] + red[2] + red[3];
  ss = red[4] + red[5] + red[6] + red[7];
  float mu = s * (1.f / DM);
  float var = ss * (1.f / DM) - mu * mu;
  float rs = rsqrtf(var + 1e-5f);
  float4 g4 = ((const float4*)gam)[t];
  float4 b4 = ((const float4*)bet)[t];
  float4 o4;
  o4.x = (x[0] - mu) * rs * g4.x + b4.x;
  o4.y = (x[1] - mu) * rs * g4.y + b4.y;
  o4.z = (x[2] - mu) * rs * g4.z + b4.z;
  o4.w = (x[3] - mu) * rs * g4.w + b4.w;
  ((float4*)(out + (size_t)rw * DM))[t] = o4;
}

// ---------------- launch ----------------

extern "C" void kernel_launch(void* const* d_in, const int* in_sizes, int n_in,
                              void* d_out, int out_size, void* d_ws, size_t ws_size,
                              hipStream_t stream)
{
  (void)in_sizes; (void)n_in; (void)out_size; (void)ws_size;
  const float* w    = (const float*)d_in[0];
  const float* r    = (const float*)d_in[1];
  const float* mems = (const float*)d_in[2];
  const float* Wqkv = (const float*)d_in[3];
  const float* Wr   = (const float*)d_in[4];
  const float* Wo   = (const float*)d_in[5];
  const float* rwb  = (const float*)d_in[6];
  const float* rrb  = (const float*)d_in[7];
  const float* gam  = (const float*)d_in[8];
  const float* bet  = (const float*)d_in[9];
  float* out = (float*)d_out;

  char* ws = (char*)d_ws;
  size_t off = 0;
  auto alloc = [&](size_t n){ char* p = ws + off; off += (n + 255) & ~(size_t)255; return p; };
  u16* catB  = (u16*)alloc((size_t)KLEN * BSZ * DM * 2);
  u16* rB    = (u16*)alloc((size_t)KLEN * DM * 2);
  u16* WqkvT = (u16*)alloc((size_t)3 * DM * DM * 2);
  u16* WrT   = (u16*)alloc((size_t)DM * DM * 2);
  u16* WoT   = (u16*)alloc((size_t)DM * DM * 2);
  u16* qBuf  = (u16*)alloc((size_t)BSZ * NH * QLEN * DH * 2);
  u16* kBp   = (u16*)alloc((size_t)BSZ * NH * KLEN * DH * 2);
  u16* vBp   = (u16*)alloc((size_t)BSZ * NH * KLEN * DH * 2);   // d-major
  u16* rhB   = (u16*)alloc((size_t)NH * KLEN * DH * 2);
  u16* av    = (u16*)alloc((size_t)QLEN * BSZ * DM * 2);        // rh tail overshoot lands here (masked)
  u16* ao    = (u16*)alloc((size_t)QLEN * BSZ * DM * 2);

  prep_k<<<dim3(15360), 256, 0, stream>>>(mems, w, r, Wqkv, WqkvT, Wr, WrT, Wo, WoT, catB, rB);
  gemm01<<<dim3(1664), 256, 0, stream>>>(catB, WqkvT, rB, WrT, qBuf, kBp, vBp, rhB);
  attn_k<<<dim3(1024), 256, 0, stream>>>(qBuf, kBp, vBp, rhB, rwb, rrb, av);
  gemm3<<<dim3(256), 256, 0, stream>>>(av, WoT, DM, ao);
  ln_k<<<dim3(4096), 256, 0, stream>>>(w, ao, gam, bet, out);
}